// Round 1
// baseline (992.645 us; speedup 1.0000x reference)
//
#include <hip/hip_runtime.h>
#include <math.h>

#define BB   4
#define C1N  128
#define C2N  256
#define HH   128
#define WW   128
#define NPT  9
#define HWN  (HH*WW)

// workspace layout (in floats)
#define WT_OFF    0                         // wT[c*9+n][o] : 1152*256 = 294912
#define WOFT_OFF  (C1N*NPT*C2N)             // wofT[c*9+tap][oc] : 128*9*18 = 20736
#define OFFP_OFF  (WOFT_OFF + C1N*9*18)     // offsets [B][18][H][W] : 1179648

// ---------------- weight transpose ----------------
__global__ __launch_bounds__(256) void transpose_w(
    const float* __restrict__ w_main, const float* __restrict__ w_off,
    float* __restrict__ ws) {
  int d = blockIdx.x * 256 + threadIdx.x;
  if (d < C1N * NPT * C2N) {
    int o = d & 255; int cn = d >> 8; int n = cn % NPT; int c = cn / NPT;
    ws[WT_OFF + d] = w_main[(o * C1N + c) * NPT + n];
  } else {
    int e = d - C1N * NPT * C2N;
    if (e < C1N * 9 * 18) {
      int oc = e % 18; int t = e / 18; int tap = t % 9; int c = t / 9;
      ws[WOFT_OFF + e] = w_off[(oc * C1N + c) * 9 + tap];
    }
  }
}

// ---------------- offset-prediction conv (3x3, pad 1) ----------------
__global__ __launch_bounds__(256) void off_conv(
    const float* __restrict__ x, const float* __restrict__ b_off,
    const float* __restrict__ ws, float* __restrict__ offp) {
  int gid = blockIdx.x * 256 + threadIdx.x;       // 0..65535
  int w = gid & (WW - 1);
  int h = (gid >> 7) & (HH - 1);
  int b = gid >> 14;
  const float* wofT = ws + WOFT_OFF;
  float acc[18];
#pragma unroll
  for (int oc = 0; oc < 18; ++oc) acc[oc] = b_off[oc];
  const float* xb = x + (size_t)b * C1N * HWN;
  for (int c = 0; c < C1N; ++c) {
    const float* xc = xb + c * HWN;
    const float* wc = wofT + c * 9 * 18;
#pragma unroll
    for (int kh = 0; kh < 3; ++kh) {
      int hh = h + kh - 1;
      bool hv = (unsigned)hh < (unsigned)HH;
#pragma unroll
      for (int kw = 0; kw < 3; ++kw) {
        int wwi = w + kw - 1;
        bool v = hv && ((unsigned)wwi < (unsigned)WW);
        float xv = v ? xc[hh * WW + wwi] : 0.f;
        const float* wp = wc + (kh * 3 + kw) * 18;
#pragma unroll
        for (int oc = 0; oc < 18; ++oc) acc[oc] = fmaf(xv, wp[oc], acc[oc]);
      }
    }
  }
#pragma unroll
  for (int oc = 0; oc < 18; ++oc)
    offp[((b * 18 + oc) * HWN) + h * WW + w] = acc[oc];
}

// ---------------- fused gather + GEMM + BN + SiLU ----------------
__global__ __launch_bounds__(256) void akconv_main(
    const float* __restrict__ x, const float* __restrict__ ws,
    const float* __restrict__ bn_gamma, const float* __restrict__ bn_beta,
    const float* __restrict__ bn_mean, const float* __restrict__ bn_var,
    float* __restrict__ out) {
  __shared__ float wgt[576][4];
  __shared__ int   sidx[576][4];
  __shared__ float xoff[2][NPT][64];

  int blk = blockIdx.x;                 // 0..1023
  int wt = blk & 1;
  int h  = (blk >> 1) & (HH - 1);
  int b  = blk >> 8;
  int w0 = wt * 64;
  int tid = threadIdx.x;

  const float* offp = ws + OFFP_OFF;

  // Phase A: bilinear sample indices + weights for 64 positions x 9 points
  for (int t = tid; t < 576; t += 256) {
    int n = t >> 6; int wl = t & 63; int wp_ = w0 + wl;
    float ox = offp[((b * 18 + n) * HWN) + h * WW + wp_];
    float oy = offp[((b * 18 + 9 + n) * HWN) + h * WW + wp_];
    float px = ox + (float)(n / 3) + (float)h;
    float py = oy + (float)(n % 3) + (float)wp_;
    px = fminf(fmaxf(px, 0.f), (float)(HH - 1));
    py = fminf(fmaxf(py, 0.f), (float)(WW - 1));
    float x0 = floorf(px);
    float y0 = floorf(py);
    float x1 = fminf(x0 + 1.f, (float)(HH - 1));
    float y1 = fminf(y0 + 1.f, (float)(WW - 1));
    float glt = (1.f + (x0 - px)) * (1.f + (y0 - py));
    float grb = (1.f - (x1 - px)) * (1.f - (y1 - py));
    float glb = (1.f + (x0 - px)) * (1.f - (y1 - py));
    float grt = (1.f - (x1 - px)) * (1.f + (y0 - py));
    int ix0 = (int)x0, iy0 = (int)y0, ix1 = (int)x1, iy1 = (int)y1;
    sidx[t][0] = ix0 * WW + iy0; wgt[t][0] = glt;
    sidx[t][1] = ix1 * WW + iy1; wgt[t][1] = grb;
    sidx[t][2] = ix0 * WW + iy1; wgt[t][2] = glb;
    sidx[t][3] = ix1 * WW + iy0; wgt[t][3] = grt;
  }
  __syncthreads();

  const float* xb = x + (size_t)b * C1N * HWN;
  const float* wT = ws + WT_OFF;

  float acc[64];
#pragma unroll
  for (int i = 0; i < 64; ++i) acc[i] = 0.f;

  int wl = tid & 63;
  int og = tid >> 6;
  int ogu = __builtin_amdgcn_readfirstlane(og);   // wave-uniform -> scalar loads

  for (int c = 0; c < C1N; ++c) {
    const float* xc = xb + c * HWN;
    int buf = c & 1;
    // gather 9x64 bilinear samples for this channel
    for (int t = tid; t < 576; t += 256) {
      float v = wgt[t][0] * xc[sidx[t][0]] + wgt[t][1] * xc[sidx[t][1]]
              + wgt[t][2] * xc[sidx[t][2]] + wgt[t][3] * xc[sidx[t][3]];
      xoff[buf][t >> 6][t & 63] = v;
    }
    __syncthreads();
    float s[NPT];
#pragma unroll
    for (int n = 0; n < NPT; ++n) s[n] = xoff[buf][n][wl];
    const float* wp = wT + c * (NPT * C2N) + ogu * 64;
#pragma unroll
    for (int n = 0; n < NPT; ++n) {
      const float* wpn = wp + n * C2N;
#pragma unroll
      for (int oi = 0; oi < 64; ++oi)
        acc[oi] = fmaf(s[n], wpn[oi], acc[oi]);
    }
    // no barrier needed before next gather: it writes the other buffer,
    // and writes to THIS buffer (c+2) are fenced by the (c+1) barrier.
  }

  // epilogue: BN (inference) + SiLU, coalesced stores along w
  float* ob = out + ((size_t)b * C2N) * HWN + h * WW + w0 + wl;
#pragma unroll
  for (int oi = 0; oi < 64; ++oi) {
    int o = ogu * 64 + oi;
    float inv = bn_gamma[o] * rsqrtf(bn_var[o] + 1e-5f);
    float sh = bn_beta[o] - bn_mean[o] * inv;
    float v = acc[oi] * inv + sh;
    float r = v / (1.f + __expf(-v));
    ob[(size_t)o * HWN] = r;
  }
}

extern "C" void kernel_launch(void* const* d_in, const int* in_sizes, int n_in,
                              void* d_out, int out_size, void* d_ws, size_t ws_size,
                              hipStream_t stream) {
  const float* x        = (const float*)d_in[0];
  const float* w_off    = (const float*)d_in[1];
  const float* b_off    = (const float*)d_in[2];
  const float* w_main   = (const float*)d_in[3];
  const float* bn_gamma = (const float*)d_in[4];
  const float* bn_beta  = (const float*)d_in[5];
  const float* bn_mean  = (const float*)d_in[6];
  const float* bn_var   = (const float*)d_in[7];
  float* ws  = (float*)d_ws;
  float* out = (float*)d_out;

  // 1) transpose weights (w_main -> k-major, w_off -> oc-minor)
  int tot = C1N * NPT * C2N + C1N * 9 * 18;
  transpose_w<<<(tot + 255) / 256, 256, 0, stream>>>(w_main, w_off, ws);
  // 2) offset-prediction conv
  off_conv<<<(BB * HWN) / 256, 256, 0, stream>>>(x, b_off, ws, ws + OFFP_OFF);
  // 3) fused bilinear gather + main contraction + BN + SiLU
  akconv_main<<<BB * HH * (WW / 64), 256, 0, stream>>>(
      x, ws, bn_gamma, bn_beta, bn_mean, bn_var, out);
}